// Round 5
// baseline (391.454 us; speedup 1.0000x reference)
//
#include <hip/hip_runtime.h>
#include <hip/hip_bf16.h>

typedef __attribute__((ext_vector_type(8))) short bf16x8;
typedef __attribute__((ext_vector_type(4))) short bf16x4;
typedef __attribute__((ext_vector_type(4))) float f32x4;

#if defined(__has_builtin)
#if __has_builtin(__builtin_amdgcn_exp2f)
#define EXP2F(x) __builtin_amdgcn_exp2f(x)
#else
#define EXP2F(x) exp2f(x)
#endif
#else
#define EXP2F(x) exp2f(x)
#endif

#define S_LEN 2048
#define NH 32
#define HD 32
#define DMODEL 1024
#define NB 2

// K=16 bf16 MFMA (B-frag k = 4*lg+j matches the 16x16x32 C-layout rows).
// Verified correct end-to-end in round 2.
static __device__ __forceinline__ f32x4 mfma16(bf16x4 a, bf16x4 b, f32x4 c) {
#if defined(__has_builtin) && __has_builtin(__builtin_amdgcn_mfma_f32_16x16x16bf16_1k)
    return __builtin_amdgcn_mfma_f32_16x16x16bf16_1k(a, b, c, 0, 0, 0);
#else
    f32x4 d;
    asm volatile("v_mfma_f32_16x16x16_bf16 %0, %1, %2, %3\n\ts_nop 7\n\ts_nop 7"
                 : "=&v"(d) : "v"(a), "v"(b), "v"(c));
    return d;
#endif
}

// ---------------------------------------------------------------------------
// Kernel 1: QKV projection. x [B,S,D] fp32 -> q,k row-major bf16 [B,H,S,d],
// v transposed bf16 [B,H,d,S]. q pre-scaled by 1/sqrt(d)*log2(e).
// (identical to round-3 passing version)
// ---------------------------------------------------------------------------
__global__ __launch_bounds__(256) void qkv_stage(
    const float* __restrict__ x,
    const float* __restrict__ wq, const float* __restrict__ bq,
    const float* __restrict__ wk, const float* __restrict__ bk,
    const float* __restrict__ wv, const float* __restrict__ bv,
    __hip_bfloat16* __restrict__ qws,
    __hip_bfloat16* __restrict__ kws,
    __hip_bfloat16* __restrict__ vtws)
{
    const int tid = threadIdx.x;
    const int cg  = blockIdx.y;
    const int rb  = blockIdx.x;
    const int c   = cg * 256 + tid;
    const int h   = c >> 5;
    const int e   = c & 31;
    const int row0 = rb * 16;
    const int b   = row0 >> 11;
    const int s0  = row0 & 2047;

    float wqc[32], wkc[32], wvc[32];
#pragma unroll
    for (int d = 0; d < 32; ++d) {
        wqc[d] = wq[d * 32 + e];
        wkc[d] = wk[d * 32 + e];
        wvc[d] = wv[d * 32 + e];
    }
    const float bqv = bq[e], bkv = bk[e], bvv = bv[e];

    __shared__ float xl[16][256];
#pragma unroll
    for (int r = 0; r < 16; ++r)
        xl[r][tid] = x[((size_t)b * S_LEN + s0 + r) * DMODEL + cg * 256 + tid];
    __syncthreads();

    const float SC = 0.1767766953f * 1.44269504089f; // 1/sqrt(32) * log2(e)
    const int hl = (tid >> 5) * 32;

    float vreg[16];
#pragma unroll
    for (int r = 0; r < 16; ++r) {
        float aq = bqv, ak = bkv, av = bvv;
#pragma unroll
        for (int d = 0; d < 32; ++d) {
            float xv = xl[r][hl + d];
            aq += xv * wqc[d];
            ak += xv * wkc[d];
            av += xv * wvc[d];
        }
        size_t base = ((size_t)(b * NH + h) * S_LEN + (s0 + r)) * HD + e;
        qws[base] = __float2bfloat16(aq * SC);
        kws[base] = __float2bfloat16(ak);
        vreg[r] = av;
    }

    unsigned int pk[8];
#pragma unroll
    for (int i = 0; i < 8; ++i) {
        __hip_bfloat16 t0 = __float2bfloat16(vreg[2 * i]);
        __hip_bfloat16 t1 = __float2bfloat16(vreg[2 * i + 1]);
        unsigned short u0 = *reinterpret_cast<unsigned short*>(&t0);
        unsigned short u1 = *reinterpret_cast<unsigned short*>(&t1);
        pk[i] = (unsigned int)u0 | ((unsigned int)u1 << 16);
    }
    size_t vbase = ((size_t)(b * NH + h) * HD + e) * S_LEN + s0;
    *reinterpret_cast<uint4*>(vtws + vbase)     = make_uint4(pk[0], pk[1], pk[2], pk[3]);
    *reinterpret_cast<uint4*>(vtws + vbase + 8) = make_uint4(pk[4], pk[5], pk[6], pk[7]);
}

// ---------------------------------------------------------------------------
// Kernel 2: wo [K][N] fp32 -> wot [N][K] bf16
// ---------------------------------------------------------------------------
__global__ __launch_bounds__(256) void wo_transpose(
    const float* __restrict__ wo, __hip_bfloat16* __restrict__ wot)
{
    __shared__ float t[64][65];
    const int bx = blockIdx.x;
    const int by = blockIdx.y;
    const int tid = threadIdx.x;
    const int col = tid & 63, row4 = tid >> 6;
#pragma unroll
    for (int i = 0; i < 16; ++i) {
        int r = i * 4 + row4;
        t[r][col] = wo[(size_t)(bx * 64 + r) * DMODEL + by * 64 + col];
    }
    __syncthreads();
#pragma unroll
    for (int i = 0; i < 16; ++i) {
        int r = i * 4 + row4;
        wot[(size_t)(by * 64 + r) * DMODEL + bx * 64 + col] =
            __float2bfloat16(t[col][r]);
    }
}

// ---------------------------------------------------------------------------
// Kernel 3: flash attention — barrier-free, LDS-free loop.
//  - XCD swizzle: all 32 q-tiles of one head -> same XCD (K/V L2-resident)
//  - swapped QK^T, fixed-offset softmax (no max/rescale/shuffles in loop)
//  - P stays in registers: S^T C-layout == K=16 MFMA B-layout
//  - K/V read directly from global (L2); no barriers -> compiler pipelines
// ---------------------------------------------------------------------------
__global__ __launch_bounds__(256) void attn_kernel(
    const __hip_bfloat16* __restrict__ qws,
    const __hip_bfloat16* __restrict__ kws,
    const __hip_bfloat16* __restrict__ vtws,
    __hip_bfloat16* __restrict__ cws)
{
    const int tid = threadIdx.x;
    const int w  = tid >> 6;
    const int ln = tid & 63;
    const int lg = ln >> 4;   // 16-lane group 0..3
    const int lm = ln & 15;

    // XCD-aware decode: xcd = bi & 7 (round-robin dispatch); 8 heads per XCD
    const int bi  = blockIdx.x;
    const int xcd = bi & 7;
    const int idx = bi >> 3;                   // 0..255
    const int qt  = idx & 31;
    const int bh  = (xcd << 3) | (idx >> 5);   // b*32+h, grouped per XCD
    const int b   = bh >> 5;
    const int h   = bh & 31;

    const __hip_bfloat16* qp = qws  + (size_t)bh * S_LEN * HD;
    const __hip_bfloat16* kp = kws  + (size_t)bh * S_LEN * HD;
    const __hip_bfloat16* vp = vtws + (size_t)bh * HD * S_LEN;

    const int qr0 = qt * 64 + w * 16;

    // Q as B-fragment: col = q = lm, k = d = lg*8+j
    bf16x8 qb = *reinterpret_cast<const bf16x8*>(qp + (size_t)(qr0 + lm) * HD + lg * 8);

    f32x4 l4 = {0.f, 0.f, 0.f, 0.f};   // per-lane partial denominator
    f32x4 o0 = {0.f, 0.f, 0.f, 0.f};   // O^T[d=4lg+r][q=lm]
    f32x4 o1 = {0.f, 0.f, 0.f, 0.f};   // O^T[16+4lg+r][q=lm]
    const f32x4 zoff = {-8.f, -8.f, -8.f, -8.f};

    for (int kt = 0; kt < S_LEN / 64; ++kt) {
        const __hip_bfloat16* kb = kp + (size_t)kt * 64 * HD;

        // S^T chunks: s[c][r] = score(q=lm, k=16c+4lg+r) - 8
        f32x4 s[4];
#pragma unroll
        for (int c = 0; c < 4; ++c) {
            bf16x8 kf = *reinterpret_cast<const bf16x8*>(
                kb + (size_t)(c * 16 + lm) * HD + lg * 8);
            s[c] = __builtin_amdgcn_mfma_f32_16x16x32_bf16(kf, qb, zoff, 0, 0, 0);
        }

        // p = exp2(s-8); accumulate denominator; pack into K=16 B-fragments
        bf16x4 pb[4];
#pragma unroll
        for (int c = 0; c < 4; ++c) {
            float p0 = EXP2F(s[c][0]);
            float p1 = EXP2F(s[c][1]);
            float p2 = EXP2F(s[c][2]);
            float p3 = EXP2F(s[c][3]);
            l4[0] += p0; l4[1] += p1; l4[2] += p2; l4[3] += p3;
            __hip_bfloat16 h0 = __float2bfloat16(p0);
            __hip_bfloat16 h1 = __float2bfloat16(p1);
            __hip_bfloat16 h2 = __float2bfloat16(p2);
            __hip_bfloat16 h3 = __float2bfloat16(p3);
            pb[c][0] = *reinterpret_cast<short*>(&h0);
            pb[c][1] = *reinterpret_cast<short*>(&h1);
            pb[c][2] = *reinterpret_cast<short*>(&h2);
            pb[c][3] = *reinterpret_cast<short*>(&h3);
        }

        // PV: O^T += V^T * P^T ; A = V^T rows (d), k = kv; B = P^T chunks
#pragma unroll
        for (int c = 0; c < 4; ++c) {
            bf16x4 va = *reinterpret_cast<const bf16x4*>(
                vp + (size_t)lm * S_LEN + kt * 64 + c * 16 + lg * 4);
            o0 = mfma16(va, pb[c], o0);
            bf16x4 vb = *reinterpret_cast<const bf16x4*>(
                vp + (size_t)(16 + lm) * S_LEN + kt * 64 + c * 16 + lg * 4);
            o1 = mfma16(vb, pb[c], o1);
        }
    }

    // final denominator: reduce partial l across the 4 lg groups of column lm
    float l = (l4[0] + l4[1]) + (l4[2] + l4[3]);
    l += __shfl_xor(l, 16);
    l += __shfl_xor(l, 32);
    float inv = 1.0f / l;

    __hip_bfloat16* cb = cws + ((size_t)b * S_LEN + qr0 + lm) * DMODEL + h * HD;
    bf16x4 w0, w1;
#pragma unroll
    for (int r = 0; r < 4; ++r) {
        __hip_bfloat16 h0 = __float2bfloat16(o0[r] * inv);
        __hip_bfloat16 h1 = __float2bfloat16(o1[r] * inv);
        w0[r] = *reinterpret_cast<short*>(&h0);
        w1[r] = *reinterpret_cast<short*>(&h1);
    }
    *reinterpret_cast<bf16x4*>(cb + lg * 4)      = w0;
    *reinterpret_cast<bf16x4*>(cb + 16 + lg * 4) = w1;
}

// ---------------------------------------------------------------------------
// Kernel 4: out = concat @ wo + bo.
// ---------------------------------------------------------------------------
__global__ __launch_bounds__(256) void out_gemm(
    const __hip_bfloat16* __restrict__ A,
    const __hip_bfloat16* __restrict__ Bt,
    const float* __restrict__ bo,
    float* __restrict__ out)
{
    const int tid = threadIdx.x;
    const int w  = tid >> 6;
    const int ln = tid & 63;
    const int lg = ln >> 4, lm = ln & 15;
    const int bi = blockIdx.x;
    const int mt = bi >> 4;
    const int nt = bi & 15;
    const int r0 = mt * 64 + w * 16;
    const int n0 = nt * 64;

    f32x4 acc[4] = {{0.f,0.f,0.f,0.f},{0.f,0.f,0.f,0.f},
                    {0.f,0.f,0.f,0.f},{0.f,0.f,0.f,0.f}};

    for (int k0 = 0; k0 < DMODEL; k0 += 32) {
        bf16x8 a = *reinterpret_cast<const bf16x8*>(
            A + (size_t)(r0 + lm) * DMODEL + k0 + lg * 8);
#pragma unroll
        for (int c = 0; c < 4; ++c) {
            bf16x8 bfr = *reinterpret_cast<const bf16x8*>(
                Bt + (size_t)(n0 + c * 16 + lm) * DMODEL + k0 + lg * 8);
            acc[c] = __builtin_amdgcn_mfma_f32_16x16x32_bf16(a, bfr, acc[c], 0, 0, 0);
        }
    }

#pragma unroll
    for (int c = 0; c < 4; ++c) {
        float bv = bo[n0 + c * 16 + lm];
#pragma unroll
        for (int r = 0; r < 4; ++r) {
            out[(size_t)(r0 + 4 * lg + r) * DMODEL + n0 + c * 16 + lm] =
                acc[c][r] + bv;
        }
    }
}

// ---------------------------------------------------------------------------
extern "C" void kernel_launch(void* const* d_in, const int* in_sizes, int n_in,
                              void* d_out, int out_size, void* d_ws, size_t ws_size,
                              hipStream_t stream)
{
    const float* x  = (const float*)d_in[0];
    const float* wq = (const float*)d_in[1];
    const float* bq = (const float*)d_in[2];
    const float* wk = (const float*)d_in[3];
    const float* bk = (const float*)d_in[4];
    const float* wv = (const float*)d_in[5];
    const float* bv = (const float*)d_in[6];
    const float* wo = (const float*)d_in[7];
    const float* bo = (const float*)d_in[8];
    float* out = (float*)d_out;

    char* ws = (char*)d_ws;
    __hip_bfloat16* qws  = (__hip_bfloat16*)(ws);                        // 8 MB
    __hip_bfloat16* kws  = (__hip_bfloat16*)(ws + ((size_t)8  << 20));   // 8 MB
    __hip_bfloat16* vtws = (__hip_bfloat16*)(ws + ((size_t)16 << 20));   // 8 MB
    __hip_bfloat16* cws  = (__hip_bfloat16*)(ws + ((size_t)24 << 20));   // 8 MB
    __hip_bfloat16* wot  = (__hip_bfloat16*)(ws + ((size_t)32 << 20));   // 2 MB

    qkv_stage<<<dim3(NB * S_LEN / 16, 4), 256, 0, stream>>>(
        x, wq, bq, wk, bk, wv, bv, qws, kws, vtws);
    wo_transpose<<<dim3(16, 16), 256, 0, stream>>>(wo, wot);
    attn_kernel<<<NB * NH * (S_LEN / 64), 256, 0, stream>>>(qws, kws, vtws, cws);
    out_gemm<<<(NB * S_LEN / 64) * (DMODEL / 64), 256, 0, stream>>>(
        cws, wot, bo, out);
}

// Round 6
// 281.889 us; speedup vs baseline: 1.3887x; 1.3887x over previous
//
#include <hip/hip_runtime.h>
#include <hip/hip_bf16.h>

typedef __attribute__((ext_vector_type(8))) short bf16x8;
typedef __attribute__((ext_vector_type(4))) short bf16x4;
typedef __attribute__((ext_vector_type(4))) float f32x4;

#if defined(__has_builtin)
#if __has_builtin(__builtin_amdgcn_exp2f)
#define EXP2F(x) __builtin_amdgcn_exp2f(x)
#else
#define EXP2F(x) exp2f(x)
#endif
#else
#define EXP2F(x) exp2f(x)
#endif

#define S_LEN 2048
#define NH 32
#define HD 32
#define DMODEL 1024
#define NB 2

// pack two fp32 -> two bf16 (RNE) in one instruction
static __device__ __forceinline__ unsigned int cvt_pk_bf16(float lo, float hi) {
    unsigned int r;
    asm("v_cvt_pk_bf16_f32 %0, %1, %2" : "=v"(r) : "v"(lo), "v"(hi));
    return r;
}

// ---------------------------------------------------------------------------
// Kernel 1: QKV projection. x [B,S,D] fp32 -> q,k row-major bf16 [B,H,S,d],
// v transposed bf16 [B,H,d,S]. q pre-scaled by 1/sqrt(d)*log2(e).
// (identical to round-3/5 passing version)
// ---------------------------------------------------------------------------
__global__ __launch_bounds__(256) void qkv_stage(
    const float* __restrict__ x,
    const float* __restrict__ wq, const float* __restrict__ bq,
    const float* __restrict__ wk, const float* __restrict__ bk,
    const float* __restrict__ wv, const float* __restrict__ bv,
    __hip_bfloat16* __restrict__ qws,
    __hip_bfloat16* __restrict__ kws,
    __hip_bfloat16* __restrict__ vtws)
{
    const int tid = threadIdx.x;
    const int cg  = blockIdx.y;
    const int rb  = blockIdx.x;
    const int c   = cg * 256 + tid;
    const int h   = c >> 5;
    const int e   = c & 31;
    const int row0 = rb * 16;
    const int b   = row0 >> 11;
    const int s0  = row0 & 2047;

    float wqc[32], wkc[32], wvc[32];
#pragma unroll
    for (int d = 0; d < 32; ++d) {
        wqc[d] = wq[d * 32 + e];
        wkc[d] = wk[d * 32 + e];
        wvc[d] = wv[d * 32 + e];
    }
    const float bqv = bq[e], bkv = bk[e], bvv = bv[e];

    __shared__ float xl[16][256];
#pragma unroll
    for (int r = 0; r < 16; ++r)
        xl[r][tid] = x[((size_t)b * S_LEN + s0 + r) * DMODEL + cg * 256 + tid];
    __syncthreads();

    const float SC = 0.1767766953f * 1.44269504089f; // 1/sqrt(32) * log2(e)
    const int hl = (tid >> 5) * 32;

    float vreg[16];
#pragma unroll
    for (int r = 0; r < 16; ++r) {
        float aq = bqv, ak = bkv, av = bvv;
#pragma unroll
        for (int d = 0; d < 32; ++d) {
            float xv = xl[r][hl + d];
            aq += xv * wqc[d];
            ak += xv * wkc[d];
            av += xv * wvc[d];
        }
        size_t base = ((size_t)(b * NH + h) * S_LEN + (s0 + r)) * HD + e;
        qws[base] = __float2bfloat16(aq * SC);
        kws[base] = __float2bfloat16(ak);
        vreg[r] = av;
    }

    unsigned int pk[8];
#pragma unroll
    for (int i = 0; i < 8; ++i) {
        __hip_bfloat16 t0 = __float2bfloat16(vreg[2 * i]);
        __hip_bfloat16 t1 = __float2bfloat16(vreg[2 * i + 1]);
        unsigned short u0 = *reinterpret_cast<unsigned short*>(&t0);
        unsigned short u1 = *reinterpret_cast<unsigned short*>(&t1);
        pk[i] = (unsigned int)u0 | ((unsigned int)u1 << 16);
    }
    size_t vbase = ((size_t)(b * NH + h) * HD + e) * S_LEN + s0;
    *reinterpret_cast<uint4*>(vtws + vbase)     = make_uint4(pk[0], pk[1], pk[2], pk[3]);
    *reinterpret_cast<uint4*>(vtws + vbase + 8) = make_uint4(pk[4], pk[5], pk[6], pk[7]);
}

// ---------------------------------------------------------------------------
// Kernel 2: wo [K][N] fp32 -> wot [N][K] bf16
// ---------------------------------------------------------------------------
__global__ __launch_bounds__(256) void wo_transpose(
    const float* __restrict__ wo, __hip_bfloat16* __restrict__ wot)
{
    __shared__ float t[64][65];
    const int bx = blockIdx.x;
    const int by = blockIdx.y;
    const int tid = threadIdx.x;
    const int col = tid & 63, row4 = tid >> 6;
#pragma unroll
    for (int i = 0; i < 16; ++i) {
        int r = i * 4 + row4;
        t[r][col] = wo[(size_t)(bx * 64 + r) * DMODEL + by * 64 + col];
    }
    __syncthreads();
#pragma unroll
    for (int i = 0; i < 16; ++i) {
        int r = i * 4 + row4;
        wot[(size_t)(by * 64 + r) * DMODEL + bx * 64 + col] =
            __float2bfloat16(t[col][r]);
    }
}

// ---------------------------------------------------------------------------
// Kernel 3: flash attention.
//  - R3-verified core: swapped QK^T (K=32 builtin ONLY), fixed-offset softmax,
//    per-wave LDS P strip, V^T direct from global. No barriers in the loop.
//  - R5-verified XCD swizzle: each head's 256KB K/V panel stays L2-resident.
//  - NEW: 2x-unrolled loop with explicit K-fragment register double-buffer
//    (kfA/kfB) so the next tile's K loads overlap the current tile's
//    MFMA/exp/LDS chain.
// ---------------------------------------------------------------------------
struct AttnAcc { f32x4 l4, o0, o1; };

static __device__ __forceinline__ void attn_body(
    int kt, const bf16x8 (&kf)[4], bf16x8 qb,
    const __hip_bfloat16* __restrict__ vp,
    __hip_bfloat16 (*plds)[72], int lg, int lm, AttnAcc& st)
{
    const f32x4 zoff = {-8.f, -8.f, -8.f, -8.f};
    f32x4 s[4];
#pragma unroll
    for (int c = 0; c < 4; ++c)
        s[c] = __builtin_amdgcn_mfma_f32_16x16x32_bf16(kf[c], qb, zoff, 0, 0, 0);

#pragma unroll
    for (int c = 0; c < 4; ++c) {
        float p0 = EXP2F(s[c][0]);
        float p1 = EXP2F(s[c][1]);
        float p2 = EXP2F(s[c][2]);
        float p3 = EXP2F(s[c][3]);
        st.l4[0] += p0; st.l4[1] += p1; st.l4[2] += p2; st.l4[3] += p3;
        *reinterpret_cast<uint2*>(&plds[lm][c * 16 + lg * 4]) =
            make_uint2(cvt_pk_bf16(p0, p1), cvt_pk_bf16(p2, p3));
    }

#pragma unroll
    for (int ks = 0; ks < 2; ++ks) {
        bf16x8 pa = *reinterpret_cast<const bf16x8*>(&plds[lm][ks * 32 + lg * 8]);
        bf16x8 va = *reinterpret_cast<const bf16x8*>(
            vp + (size_t)lm * S_LEN + kt * 64 + ks * 32 + lg * 8);
        st.o0 = __builtin_amdgcn_mfma_f32_16x16x32_bf16(va, pa, st.o0, 0, 0, 0);
        bf16x8 vb = *reinterpret_cast<const bf16x8*>(
            vp + (size_t)(16 + lm) * S_LEN + kt * 64 + ks * 32 + lg * 8);
        st.o1 = __builtin_amdgcn_mfma_f32_16x16x32_bf16(vb, pa, st.o1, 0, 0, 0);
    }
}

__global__ __launch_bounds__(256) void attn_kernel(
    const __hip_bfloat16* __restrict__ qws,
    const __hip_bfloat16* __restrict__ kws,
    const __hip_bfloat16* __restrict__ vtws,
    __hip_bfloat16* __restrict__ cws)
{
    const int tid = threadIdx.x;
    const int w  = tid >> 6;
    const int ln = tid & 63;
    const int lg = ln >> 4;   // 16-lane group 0..3
    const int lm = ln & 15;

    // XCD-aware decode (R5-verified): heads 8x..8x+7 pinned to XCD x
    const int bi  = blockIdx.x;
    const int xcd = bi & 7;
    const int idx = bi >> 3;                   // 0..255
    const int qt  = idx & 31;
    const int bh  = (xcd << 3) | (idx >> 5);   // b*32+h
    const int b   = bh >> 5;
    const int h   = bh & 31;

    const __hip_bfloat16* qp = qws  + (size_t)bh * S_LEN * HD;
    const __hip_bfloat16* kp = kws  + (size_t)bh * S_LEN * HD;
    const __hip_bfloat16* vp = vtws + (size_t)bh * HD * S_LEN;

    const int qr0 = qt * 64 + w * 16;

    // Q as B-fragment: col = q = lm, k = d = lg*8+j
    bf16x8 qb = *reinterpret_cast<const bf16x8*>(qp + (size_t)(qr0 + lm) * HD + lg * 8);

    __shared__ __align__(16) __hip_bfloat16 plds_all[4][16][72];
    __hip_bfloat16 (*plds)[72] = plds_all[w];

    AttnAcc st;
    st.l4 = {0.f, 0.f, 0.f, 0.f};
    st.o0 = {0.f, 0.f, 0.f, 0.f};
    st.o1 = {0.f, 0.f, 0.f, 0.f};

    const size_t koff = (size_t)lm * HD + lg * 8;   // within a 64xHD K tile: row c*16+lm

    // prologue: K fragments for tile 0
    bf16x8 kfA[4], kfB[4];
#pragma unroll
    for (int c = 0; c < 4; ++c)
        kfA[c] = *reinterpret_cast<const bf16x8*>(kp + (size_t)c * 16 * HD + koff);

    for (int kt = 0; kt < S_LEN / 64; kt += 2) {
        // iter kt: prefetch kt+1 into kfB, compute with kfA
        {
            const __hip_bfloat16* kbn = kp + (size_t)(kt + 1) * 64 * HD;
#pragma unroll
            for (int c = 0; c < 4; ++c)
                kfB[c] = *reinterpret_cast<const bf16x8*>(kbn + (size_t)c * 16 * HD + koff);
            attn_body(kt, kfA, qb, vp, plds, lg, lm, st);
        }
        // iter kt+1: prefetch kt+2 into kfA, compute with kfB
        {
            if (kt + 2 < S_LEN / 64) {
                const __hip_bfloat16* kbn = kp + (size_t)(kt + 2) * 64 * HD;
#pragma unroll
                for (int c = 0; c < 4; ++c)
                    kfA[c] = *reinterpret_cast<const bf16x8*>(kbn + (size_t)c * 16 * HD + koff);
            }
            attn_body(kt + 1, kfB, qb, vp, plds, lg, lm, st);
        }
    }

    // final denominator: reduce partial l across the 4 lg groups of column lm
    float l = (st.l4[0] + st.l4[1]) + (st.l4[2] + st.l4[3]);
    l += __shfl_xor(l, 16);
    l += __shfl_xor(l, 32);
    float inv = 1.0f / l;

    __hip_bfloat16* cb = cws + ((size_t)b * S_LEN + qr0 + lm) * DMODEL + h * HD;
    union { unsigned int u[2]; bf16x4 v; } w0, w1;
    w0.u[0] = cvt_pk_bf16(st.o0[0] * inv, st.o0[1] * inv);
    w0.u[1] = cvt_pk_bf16(st.o0[2] * inv, st.o0[3] * inv);
    w1.u[0] = cvt_pk_bf16(st.o1[0] * inv, st.o1[1] * inv);
    w1.u[1] = cvt_pk_bf16(st.o1[2] * inv, st.o1[3] * inv);
    *reinterpret_cast<bf16x4*>(cb + lg * 4)      = w0.v;
    *reinterpret_cast<bf16x4*>(cb + 16 + lg * 4) = w1.v;
}

// ---------------------------------------------------------------------------
// Kernel 4: out = concat @ wo + bo.
// ---------------------------------------------------------------------------
__global__ __launch_bounds__(256) void out_gemm(
    const __hip_bfloat16* __restrict__ A,
    const __hip_bfloat16* __restrict__ Bt,
    const float* __restrict__ bo,
    float* __restrict__ out)
{
    const int tid = threadIdx.x;
    const int w  = tid >> 6;
    const int ln = tid & 63;
    const int lg = ln >> 4, lm = ln & 15;
    const int bi = blockIdx.x;
    const int mt = bi >> 4;
    const int nt = bi & 15;
    const int r0 = mt * 64 + w * 16;
    const int n0 = nt * 64;

    f32x4 acc[4] = {{0.f,0.f,0.f,0.f},{0.f,0.f,0.f,0.f},
                    {0.f,0.f,0.f,0.f},{0.f,0.f,0.f,0.f}};

    for (int k0 = 0; k0 < DMODEL; k0 += 32) {
        bf16x8 a = *reinterpret_cast<const bf16x8*>(
            A + (size_t)(r0 + lm) * DMODEL + k0 + lg * 8);
#pragma unroll
        for (int c = 0; c < 4; ++c) {
            bf16x8 bfr = *reinterpret_cast<const bf16x8*>(
                Bt + (size_t)(n0 + c * 16 + lm) * DMODEL + k0 + lg * 8);
            acc[c] = __builtin_amdgcn_mfma_f32_16x16x32_bf16(a, bfr, acc[c], 0, 0, 0);
        }
    }

#pragma unroll
    for (int c = 0; c < 4; ++c) {
        float bv = bo[n0 + c * 16 + lm];
#pragma unroll
        for (int r = 0; r < 4; ++r) {
            out[(size_t)(r0 + 4 * lg + r) * DMODEL + n0 + c * 16 + lm] =
                acc[c][r] + bv;
        }
    }
}

// ---------------------------------------------------------------------------
extern "C" void kernel_launch(void* const* d_in, const int* in_sizes, int n_in,
                              void* d_out, int out_size, void* d_ws, size_t ws_size,
                              hipStream_t stream)
{
    const float* x  = (const float*)d_in[0];
    const float* wq = (const float*)d_in[1];
    const float* bq = (const float*)d_in[2];
    const float* wk = (const float*)d_in[3];
    const float* bk = (const float*)d_in[4];
    const float* wv = (const float*)d_in[5];
    const float* bv = (const float*)d_in[6];
    const float* wo = (const float*)d_in[7];
    const float* bo = (const float*)d_in[8];
    float* out = (float*)d_out;

    char* ws = (char*)d_ws;
    __hip_bfloat16* qws  = (__hip_bfloat16*)(ws);                        // 8 MB
    __hip_bfloat16* kws  = (__hip_bfloat16*)(ws + ((size_t)8  << 20));   // 8 MB
    __hip_bfloat16* vtws = (__hip_bfloat16*)(ws + ((size_t)16 << 20));   // 8 MB
    __hip_bfloat16* cws  = (__hip_bfloat16*)(ws + ((size_t)24 << 20));   // 8 MB
    __hip_bfloat16* wot  = (__hip_bfloat16*)(ws + ((size_t)32 << 20));   // 2 MB

    qkv_stage<<<dim3(NB * S_LEN / 16, 4), 256, 0, stream>>>(
        x, wq, bq, wk, bk, wv, bv, qws, kws, vtws);
    wo_transpose<<<dim3(16, 16), 256, 0, stream>>>(wo, wot);
    attn_kernel<<<NB * NH * (S_LEN / 64), 256, 0, stream>>>(qws, kws, vtws, cws);
    out_gemm<<<(NB * S_LEN / 64) * (DMODEL / 64), 256, 0, stream>>>(
        cws, wot, bo, out);
}

// Round 7
// 172.281 us; speedup vs baseline: 2.2722x; 1.6362x over previous
//
#include <hip/hip_runtime.h>
#include <hip/hip_bf16.h>

typedef __attribute__((ext_vector_type(8))) short bf16x8;
typedef __attribute__((ext_vector_type(4))) short bf16x4;
typedef __attribute__((ext_vector_type(4))) float f32x4;

#if defined(__has_builtin)
#if __has_builtin(__builtin_amdgcn_exp2f)
#define EXP2F(x) __builtin_amdgcn_exp2f(x)
#else
#define EXP2F(x) exp2f(x)
#endif
#else
#define EXP2F(x) exp2f(x)
#endif

#define S_LEN 2048
#define NH 32
#define HD 32
#define DMODEL 1024
#define NB 2

// pack two fp32 -> two bf16 (RNE) in one instruction
static __device__ __forceinline__ unsigned int cvt_pk_bf16(float lo, float hi) {
    unsigned int r;
    asm("v_cvt_pk_bf16_f32 %0, %1, %2" : "=v"(r) : "v"(lo), "v"(hi));
    return r;
}

// ---------------------------------------------------------------------------
// Kernel 1: QKV projection. x [B,S,D] fp32 -> q,k row-major bf16 [B,H,S,d],
// v transposed bf16 [B,H,d,S]. q pre-scaled by 1/sqrt(d)*log2(e).
// (identical to round-3/5/6 passing version)
// ---------------------------------------------------------------------------
__global__ __launch_bounds__(256) void qkv_stage(
    const float* __restrict__ x,
    const float* __restrict__ wq, const float* __restrict__ bq,
    const float* __restrict__ wk, const float* __restrict__ bk,
    const float* __restrict__ wv, const float* __restrict__ bv,
    __hip_bfloat16* __restrict__ qws,
    __hip_bfloat16* __restrict__ kws,
    __hip_bfloat16* __restrict__ vtws)
{
    const int tid = threadIdx.x;
    const int cg  = blockIdx.y;
    const int rb  = blockIdx.x;
    const int c   = cg * 256 + tid;
    const int h   = c >> 5;
    const int e   = c & 31;
    const int row0 = rb * 16;
    const int b   = row0 >> 11;
    const int s0  = row0 & 2047;

    float wqc[32], wkc[32], wvc[32];
#pragma unroll
    for (int d = 0; d < 32; ++d) {
        wqc[d] = wq[d * 32 + e];
        wkc[d] = wk[d * 32 + e];
        wvc[d] = wv[d * 32 + e];
    }
    const float bqv = bq[e], bkv = bk[e], bvv = bv[e];

    __shared__ float xl[16][256];
#pragma unroll
    for (int r = 0; r < 16; ++r)
        xl[r][tid] = x[((size_t)b * S_LEN + s0 + r) * DMODEL + cg * 256 + tid];
    __syncthreads();

    const float SC = 0.1767766953f * 1.44269504089f; // 1/sqrt(32) * log2(e)
    const int hl = (tid >> 5) * 32;

    float vreg[16];
#pragma unroll
    for (int r = 0; r < 16; ++r) {
        float aq = bqv, ak = bkv, av = bvv;
#pragma unroll
        for (int d = 0; d < 32; ++d) {
            float xv = xl[r][hl + d];
            aq += xv * wqc[d];
            ak += xv * wkc[d];
            av += xv * wvc[d];
        }
        size_t base = ((size_t)(b * NH + h) * S_LEN + (s0 + r)) * HD + e;
        qws[base] = __float2bfloat16(aq * SC);
        kws[base] = __float2bfloat16(ak);
        vreg[r] = av;
    }

    unsigned int pk[8];
#pragma unroll
    for (int i = 0; i < 8; ++i) {
        __hip_bfloat16 t0 = __float2bfloat16(vreg[2 * i]);
        __hip_bfloat16 t1 = __float2bfloat16(vreg[2 * i + 1]);
        unsigned short u0 = *reinterpret_cast<unsigned short*>(&t0);
        unsigned short u1 = *reinterpret_cast<unsigned short*>(&t1);
        pk[i] = (unsigned int)u0 | ((unsigned int)u1 << 16);
    }
    size_t vbase = ((size_t)(b * NH + h) * HD + e) * S_LEN + s0;
    *reinterpret_cast<uint4*>(vtws + vbase)     = make_uint4(pk[0], pk[1], pk[2], pk[3]);
    *reinterpret_cast<uint4*>(vtws + vbase + 8) = make_uint4(pk[4], pk[5], pk[6], pk[7]);
}

// ---------------------------------------------------------------------------
// Kernel 2: wo [K][N] fp32 -> wot [N][K] bf16
// ---------------------------------------------------------------------------
__global__ __launch_bounds__(256) void wo_transpose(
    const float* __restrict__ wo, __hip_bfloat16* __restrict__ wot)
{
    __shared__ float t[64][65];
    const int bx = blockIdx.x;
    const int by = blockIdx.y;
    const int tid = threadIdx.x;
    const int col = tid & 63, row4 = tid >> 6;
#pragma unroll
    for (int i = 0; i < 16; ++i) {
        int r = i * 4 + row4;
        t[r][col] = wo[(size_t)(bx * 64 + r) * DMODEL + by * 64 + col];
    }
    __syncthreads();
#pragma unroll
    for (int i = 0; i < 16; ++i) {
        int r = i * 4 + row4;
        wot[(size_t)(by * 64 + r) * DMODEL + bx * 64 + col] =
            __float2bfloat16(t[col][r]);
    }
}

// ---------------------------------------------------------------------------
// Kernel 3: flash attention with BLOCK-SHARED K/V LDS staging (reg-staged,
// race-free: global->reg, barrier, ds_write, barrier, compute; next-tile
// loads issued before compute so latency hides under MFMA/exp).
//  - K tile [64 kv][32 d] staged linearly (4 KB).
//  - V^T tile [32 d][64 kv] staged with 16B-slot XOR swizzle j^=(row&7)
//    applied on the SOURCE address (read applies the same XOR) -> LDS reads
//    bank-balanced.
//  - Swapped QK^T (K=32 builtin), fixed-offset softmax, per-wave LDS P strip.
//  - R5-verified XCD swizzle keeps each head's K/V panel L2-resident.
// ---------------------------------------------------------------------------
__global__ __launch_bounds__(256) void attn_kernel(
    const __hip_bfloat16* __restrict__ qws,
    const __hip_bfloat16* __restrict__ kws,
    const __hip_bfloat16* __restrict__ vtws,
    __hip_bfloat16* __restrict__ cws)
{
    const int tid = threadIdx.x;
    const int w  = tid >> 6;
    const int ln = tid & 63;
    const int lg = ln >> 4;   // 16-lane group 0..3
    const int lm = ln & 15;

    // XCD-aware decode (R5-verified): heads 8x..8x+7 pinned to XCD x
    const int bi  = blockIdx.x;
    const int xcd = bi & 7;
    const int idx = bi >> 3;                   // 0..255
    const int qt  = idx & 31;
    const int bh  = (xcd << 3) | (idx >> 5);   // b*32+h
    const int b   = bh >> 5;
    const int h   = bh & 31;

    const __hip_bfloat16* qp = qws + (size_t)bh * S_LEN * HD;
    const char* kpb = (const char*)(kws  + (size_t)bh * S_LEN * HD);
    const char* vpb = (const char*)(vtws + (size_t)bh * HD * S_LEN);

    const int qr0 = qt * 64 + w * 16;

    // Q as B-fragment: col = q = lm, k = d = lg*8+j
    bf16x8 qb = *reinterpret_cast<const bf16x8*>(qp + (size_t)(qr0 + lm) * HD + lg * 8);

    // LDS: K tile [0,4096) linear; V tile [4096,8192) slot-swizzled
    __shared__ __align__(16) char kv[8192];
    __shared__ __align__(16) __hip_bfloat16 plds_all[4][16][72];
    __hip_bfloat16 (*plds)[72] = plds_all[w];

    f32x4 l4 = {0.f, 0.f, 0.f, 0.f};
    f32x4 o0 = {0.f, 0.f, 0.f, 0.f};   // O^T[d=4lg+r][q=lm]
    f32x4 o1 = {0.f, 0.f, 0.f, 0.f};   // O^T[16+4lg+r][q=lm]
    const f32x4 zoff = {-8.f, -8.f, -8.f, -8.f};

    // staging addresses: thread tid owns 16B slot tid of each tile
    const int vrow  = tid >> 3;                       // V^T row (d), 0..31
    const int vslot = tid & 7;                        // 16B slot within row
    const size_t vsrc = (size_t)vrow * (S_LEN * 2) +
                        (size_t)(vslot ^ (vrow & 7)) * 16;   // swizzled source

    // prologue: load tile 0 into registers
    uint4 kreg = *reinterpret_cast<const uint4*>(kpb + tid * 16);
    uint4 vreg = *reinterpret_cast<const uint4*>(vpb + vsrc);

    for (int kt = 0; kt < S_LEN / 64; ++kt) {
        if (kt) __syncthreads();                      // readers done with buffer
        *reinterpret_cast<uint4*>(&kv[tid * 16])        = kreg;
        *reinterpret_cast<uint4*>(&kv[4096 + tid * 16]) = vreg;
        __syncthreads();                              // staged data visible
        if (kt + 1 < S_LEN / 64) {                    // issue next-tile loads now
            kreg = *reinterpret_cast<const uint4*>(
                kpb + (size_t)(kt + 1) * 4096 + tid * 16);
            vreg = *reinterpret_cast<const uint4*>(
                vpb + vsrc + (size_t)(kt + 1) * 128);
        }

        // S^T chunks: s[c][r] = score(q=lm, k=16c+4lg+r) - 8
        f32x4 s[4];
#pragma unroll
        for (int c = 0; c < 4; ++c) {
            bf16x8 kf = *reinterpret_cast<const bf16x8*>(
                &kv[c * 1024 + lm * 64 + lg * 16]);
            s[c] = __builtin_amdgcn_mfma_f32_16x16x32_bf16(kf, qb, zoff, 0, 0, 0);
        }

        // p = exp2(s-8); accumulate denominator; pack into P[q][k] LDS strip
#pragma unroll
        for (int c = 0; c < 4; ++c) {
            float p0 = EXP2F(s[c][0]);
            float p1 = EXP2F(s[c][1]);
            float p2 = EXP2F(s[c][2]);
            float p3 = EXP2F(s[c][3]);
            l4[0] += p0; l4[1] += p1; l4[2] += p2; l4[3] += p3;
            *reinterpret_cast<uint2*>(&plds[lm][c * 16 + lg * 4]) =
                make_uint2(cvt_pk_bf16(p0, p1), cvt_pk_bf16(p2, p3));
        }

        // PV: O^T += V^T * P^T; A = V^T rows from swizzled LDS (16B reads)
#pragma unroll
        for (int ks = 0; ks < 2; ++ks) {
            bf16x8 pa = *reinterpret_cast<const bf16x8*>(
                &plds[lm][ks * 32 + lg * 8]);
            int j = (ks * 4 + lg) ^ (lm & 7);
            bf16x8 va = *reinterpret_cast<const bf16x8*>(
                &kv[4096 + lm * 128 + j * 16]);
            o0 = __builtin_amdgcn_mfma_f32_16x16x32_bf16(va, pa, o0, 0, 0, 0);
            bf16x8 vb = *reinterpret_cast<const bf16x8*>(
                &kv[4096 + (lm + 16) * 128 + j * 16]);
            o1 = __builtin_amdgcn_mfma_f32_16x16x32_bf16(vb, pa, o1, 0, 0, 0);
        }
    }

    // final denominator: reduce partial l across the 4 lg groups of column lm
    float l = (l4[0] + l4[1]) + (l4[2] + l4[3]);
    l += __shfl_xor(l, 16);
    l += __shfl_xor(l, 32);
    float inv = 1.0f / l;

    __hip_bfloat16* cb = cws + ((size_t)b * S_LEN + qr0 + lm) * DMODEL + h * HD;
    union { unsigned int u[2]; bf16x4 v; } w0, w1;
    w0.u[0] = cvt_pk_bf16(o0[0] * inv, o0[1] * inv);
    w0.u[1] = cvt_pk_bf16(o0[2] * inv, o0[3] * inv);
    w1.u[0] = cvt_pk_bf16(o1[0] * inv, o1[1] * inv);
    w1.u[1] = cvt_pk_bf16(o1[2] * inv, o1[3] * inv);
    *reinterpret_cast<bf16x4*>(cb + lg * 4)      = w0.v;
    *reinterpret_cast<bf16x4*>(cb + 16 + lg * 4) = w1.v;
}

// ---------------------------------------------------------------------------
// Kernel 4: out = concat @ wo + bo.
// ---------------------------------------------------------------------------
__global__ __launch_bounds__(256) void out_gemm(
    const __hip_bfloat16* __restrict__ A,
    const __hip_bfloat16* __restrict__ Bt,
    const float* __restrict__ bo,
    float* __restrict__ out)
{
    const int tid = threadIdx.x;
    const int w  = tid >> 6;
    const int ln = tid & 63;
    const int lg = ln >> 4, lm = ln & 15;
    const int bi = blockIdx.x;
    const int mt = bi >> 4;
    const int nt = bi & 15;
    const int r0 = mt * 64 + w * 16;
    const int n0 = nt * 64;

    f32x4 acc[4] = {{0.f,0.f,0.f,0.f},{0.f,0.f,0.f,0.f},
                    {0.f,0.f,0.f,0.f},{0.f,0.f,0.f,0.f}};

    for (int k0 = 0; k0 < DMODEL; k0 += 32) {
        bf16x8 a = *reinterpret_cast<const bf16x8*>(
            A + (size_t)(r0 + lm) * DMODEL + k0 + lg * 8);
#pragma unroll
        for (int c = 0; c < 4; ++c) {
            bf16x8 bfr = *reinterpret_cast<const bf16x8*>(
                Bt + (size_t)(n0 + c * 16 + lm) * DMODEL + k0 + lg * 8);
            acc[c] = __builtin_amdgcn_mfma_f32_16x16x32_bf16(a, bfr, acc[c], 0, 0, 0);
        }
    }

#pragma unroll
    for (int c = 0; c < 4; ++c) {
        float bv = bo[n0 + c * 16 + lm];
#pragma unroll
        for (int r = 0; r < 4; ++r) {
            out[(size_t)(r0 + 4 * lg + r) * DMODEL + n0 + c * 16 + lm] =
                acc[c][r] + bv;
        }
    }
}

// ---------------------------------------------------------------------------
extern "C" void kernel_launch(void* const* d_in, const int* in_sizes, int n_in,
                              void* d_out, int out_size, void* d_ws, size_t ws_size,
                              hipStream_t stream)
{
    const float* x  = (const float*)d_in[0];
    const float* wq = (const float*)d_in[1];
    const float* bq = (const float*)d_in[2];
    const float* wk = (const float*)d_in[3];
    const float* bk = (const float*)d_in[4];
    const float* wv = (const float*)d_in[5];
    const float* bv = (const float*)d_in[6];
    const float* wo = (const float*)d_in[7];
    const float* bo = (const float*)d_in[8];
    float* out = (float*)d_out;

    char* ws = (char*)d_ws;
    __hip_bfloat16* qws  = (__hip_bfloat16*)(ws);                        // 8 MB
    __hip_bfloat16* kws  = (__hip_bfloat16*)(ws + ((size_t)8  << 20));   // 8 MB
    __hip_bfloat16* vtws = (__hip_bfloat16*)(ws + ((size_t)16 << 20));   // 8 MB
    __hip_bfloat16* cws  = (__hip_bfloat16*)(ws + ((size_t)24 << 20));   // 8 MB
    __hip_bfloat16* wot  = (__hip_bfloat16*)(ws + ((size_t)32 << 20));   // 2 MB

    qkv_stage<<<dim3(NB * S_LEN / 16, 4), 256, 0, stream>>>(
        x, wq, bq, wk, bk, wv, bv, qws, kws, vtws);
    wo_transpose<<<dim3(16, 16), 256, 0, stream>>>(wo, wot);
    attn_kernel<<<NB * NH * (S_LEN / 64), 256, 0, stream>>>(qws, kws, vtws, cws);
    out_gemm<<<(NB * S_LEN / 64) * (DMODEL / 64), 256, 0, stream>>>(
        cws, wot, bo, out);
}

// Round 8
// 116.674 us; speedup vs baseline: 3.3551x; 1.4766x over previous
//
#include <hip/hip_runtime.h>
#include <hip/hip_bf16.h>

typedef __attribute__((ext_vector_type(8))) short bf16x8;
typedef __attribute__((ext_vector_type(4))) short bf16x4;
typedef __attribute__((ext_vector_type(4))) float f32x4;

#if defined(__has_builtin)
#if __has_builtin(__builtin_amdgcn_exp2f)
#define EXP2F(x) __builtin_amdgcn_exp2f(x)
#else
#define EXP2F(x) exp2f(x)
#endif
#else
#define EXP2F(x) exp2f(x)
#endif

#define S_LEN 2048
#define NH 32
#define HD 32
#define DMODEL 1024
#define NB 2

// pack two fp32 -> two bf16 (RNE) in one instruction
static __device__ __forceinline__ unsigned int cvt_pk_bf16(float lo, float hi) {
    unsigned int r;
    asm("v_cvt_pk_bf16_f32 %0, %1, %2" : "=v"(r) : "v"(lo), "v"(hi));
    return r;
}

// ---------------------------------------------------------------------------
// Kernel 1: QKV projection. x [B,S,D] fp32 -> q,k row-major bf16 [B,H,S,d],
// v transposed bf16 [B,H,d,S]. q pre-scaled by 1/sqrt(d)*log2(e).
// (identical to round-3/5/6/7 passing version)
// ---------------------------------------------------------------------------
__global__ __launch_bounds__(256) void qkv_stage(
    const float* __restrict__ x,
    const float* __restrict__ wq, const float* __restrict__ bq,
    const float* __restrict__ wk, const float* __restrict__ bk,
    const float* __restrict__ wv, const float* __restrict__ bv,
    __hip_bfloat16* __restrict__ qws,
    __hip_bfloat16* __restrict__ kws,
    __hip_bfloat16* __restrict__ vtws)
{
    const int tid = threadIdx.x;
    const int cg  = blockIdx.y;
    const int rb  = blockIdx.x;
    const int c   = cg * 256 + tid;
    const int h   = c >> 5;
    const int e   = c & 31;
    const int row0 = rb * 16;
    const int b   = row0 >> 11;
    const int s0  = row0 & 2047;

    float wqc[32], wkc[32], wvc[32];
#pragma unroll
    for (int d = 0; d < 32; ++d) {
        wqc[d] = wq[d * 32 + e];
        wkc[d] = wk[d * 32 + e];
        wvc[d] = wv[d * 32 + e];
    }
    const float bqv = bq[e], bkv = bk[e], bvv = bv[e];

    __shared__ float xl[16][256];
#pragma unroll
    for (int r = 0; r < 16; ++r)
        xl[r][tid] = x[((size_t)b * S_LEN + s0 + r) * DMODEL + cg * 256 + tid];
    __syncthreads();

    const float SC = 0.1767766953f * 1.44269504089f; // 1/sqrt(32) * log2(e)
    const int hl = (tid >> 5) * 32;

    float vreg[16];
#pragma unroll
    for (int r = 0; r < 16; ++r) {
        float aq = bqv, ak = bkv, av = bvv;
#pragma unroll
        for (int d = 0; d < 32; ++d) {
            float xv = xl[r][hl + d];
            aq += xv * wqc[d];
            ak += xv * wkc[d];
            av += xv * wvc[d];
        }
        size_t base = ((size_t)(b * NH + h) * S_LEN + (s0 + r)) * HD + e;
        qws[base] = __float2bfloat16(aq * SC);
        kws[base] = __float2bfloat16(ak);
        vreg[r] = av;
    }

    unsigned int pk[8];
#pragma unroll
    for (int i = 0; i < 8; ++i) {
        __hip_bfloat16 t0 = __float2bfloat16(vreg[2 * i]);
        __hip_bfloat16 t1 = __float2bfloat16(vreg[2 * i + 1]);
        unsigned short u0 = *reinterpret_cast<unsigned short*>(&t0);
        unsigned short u1 = *reinterpret_cast<unsigned short*>(&t1);
        pk[i] = (unsigned int)u0 | ((unsigned int)u1 << 16);
    }
    size_t vbase = ((size_t)(b * NH + h) * HD + e) * S_LEN + s0;
    *reinterpret_cast<uint4*>(vtws + vbase)     = make_uint4(pk[0], pk[1], pk[2], pk[3]);
    *reinterpret_cast<uint4*>(vtws + vbase + 8) = make_uint4(pk[4], pk[5], pk[6], pk[7]);
}

// ---------------------------------------------------------------------------
// Kernel 2: wo [K][N] fp32 -> wot [N][K] bf16
// ---------------------------------------------------------------------------
__global__ __launch_bounds__(256) void wo_transpose(
    const float* __restrict__ wo, __hip_bfloat16* __restrict__ wot)
{
    __shared__ float t[64][65];
    const int bx = blockIdx.x;
    const int by = blockIdx.y;
    const int tid = threadIdx.x;
    const int col = tid & 63, row4 = tid >> 6;
#pragma unroll
    for (int i = 0; i < 16; ++i) {
        int r = i * 4 + row4;
        t[r][col] = wo[(size_t)(bx * 64 + r) * DMODEL + by * 64 + col];
    }
    __syncthreads();
#pragma unroll
    for (int i = 0; i < 16; ++i) {
        int r = i * 4 + row4;
        wot[(size_t)(by * 64 + r) * DMODEL + bx * 64 + col] =
            __float2bfloat16(t[col][r]);
    }
}

// ---------------------------------------------------------------------------
// Kernel 3: flash attention (unchanged from round-7 passing version).
// ---------------------------------------------------------------------------
__global__ __launch_bounds__(256) void attn_kernel(
    const __hip_bfloat16* __restrict__ qws,
    const __hip_bfloat16* __restrict__ kws,
    const __hip_bfloat16* __restrict__ vtws,
    __hip_bfloat16* __restrict__ cws)
{
    const int tid = threadIdx.x;
    const int w  = tid >> 6;
    const int ln = tid & 63;
    const int lg = ln >> 4;   // 16-lane group 0..3
    const int lm = ln & 15;

    // XCD-aware decode (R5-verified): heads 8x..8x+7 pinned to XCD x
    const int bi  = blockIdx.x;
    const int xcd = bi & 7;
    const int idx = bi >> 3;                   // 0..255
    const int qt  = idx & 31;
    const int bh  = (xcd << 3) | (idx >> 5);   // b*32+h
    const int b   = bh >> 5;
    const int h   = bh & 31;

    const __hip_bfloat16* qp = qws + (size_t)bh * S_LEN * HD;
    const char* kpb = (const char*)(kws  + (size_t)bh * S_LEN * HD);
    const char* vpb = (const char*)(vtws + (size_t)bh * HD * S_LEN);

    const int qr0 = qt * 64 + w * 16;

    // Q as B-fragment: col = q = lm, k = d = lg*8+j
    bf16x8 qb = *reinterpret_cast<const bf16x8*>(qp + (size_t)(qr0 + lm) * HD + lg * 8);

    // LDS: K tile [0,4096) linear; V tile [4096,8192) slot-swizzled
    __shared__ __align__(16) char kv[8192];
    __shared__ __align__(16) __hip_bfloat16 plds_all[4][16][72];
    __hip_bfloat16 (*plds)[72] = plds_all[w];

    f32x4 l4 = {0.f, 0.f, 0.f, 0.f};
    f32x4 o0 = {0.f, 0.f, 0.f, 0.f};   // O^T[d=4lg+r][q=lm]
    f32x4 o1 = {0.f, 0.f, 0.f, 0.f};   // O^T[16+4lg+r][q=lm]
    const f32x4 zoff = {-8.f, -8.f, -8.f, -8.f};

    // staging addresses: thread tid owns 16B slot tid of each tile
    const int vrow  = tid >> 3;                       // V^T row (d), 0..31
    const int vslot = tid & 7;                        // 16B slot within row
    const size_t vsrc = (size_t)vrow * (S_LEN * 2) +
                        (size_t)(vslot ^ (vrow & 7)) * 16;   // swizzled source

    // prologue: load tile 0 into registers
    uint4 kreg = *reinterpret_cast<const uint4*>(kpb + tid * 16);
    uint4 vreg = *reinterpret_cast<const uint4*>(vpb + vsrc);

    for (int kt = 0; kt < S_LEN / 64; ++kt) {
        if (kt) __syncthreads();                      // readers done with buffer
        *reinterpret_cast<uint4*>(&kv[tid * 16])        = kreg;
        *reinterpret_cast<uint4*>(&kv[4096 + tid * 16]) = vreg;
        __syncthreads();                              // staged data visible
        if (kt + 1 < S_LEN / 64) {                    // issue next-tile loads now
            kreg = *reinterpret_cast<const uint4*>(
                kpb + (size_t)(kt + 1) * 4096 + tid * 16);
            vreg = *reinterpret_cast<const uint4*>(
                vpb + vsrc + (size_t)(kt + 1) * 128);
        }

        // S^T chunks: s[c][r] = score(q=lm, k=16c+4lg+r) - 8
        f32x4 s[4];
#pragma unroll
        for (int c = 0; c < 4; ++c) {
            bf16x8 kf = *reinterpret_cast<const bf16x8*>(
                &kv[c * 1024 + lm * 64 + lg * 16]);
            s[c] = __builtin_amdgcn_mfma_f32_16x16x32_bf16(kf, qb, zoff, 0, 0, 0);
        }

        // p = exp2(s-8); accumulate denominator; pack into P[q][k] LDS strip
#pragma unroll
        for (int c = 0; c < 4; ++c) {
            float p0 = EXP2F(s[c][0]);
            float p1 = EXP2F(s[c][1]);
            float p2 = EXP2F(s[c][2]);
            float p3 = EXP2F(s[c][3]);
            l4[0] += p0; l4[1] += p1; l4[2] += p2; l4[3] += p3;
            *reinterpret_cast<uint2*>(&plds[lm][c * 16 + lg * 4]) =
                make_uint2(cvt_pk_bf16(p0, p1), cvt_pk_bf16(p2, p3));
        }

        // PV: O^T += V^T * P^T; A = V^T rows from swizzled LDS (16B reads)
#pragma unroll
        for (int ks = 0; ks < 2; ++ks) {
            bf16x8 pa = *reinterpret_cast<const bf16x8*>(
                &plds[lm][ks * 32 + lg * 8]);
            int j = (ks * 4 + lg) ^ (lm & 7);
            bf16x8 va = *reinterpret_cast<const bf16x8*>(
                &kv[4096 + lm * 128 + j * 16]);
            o0 = __builtin_amdgcn_mfma_f32_16x16x32_bf16(va, pa, o0, 0, 0, 0);
            bf16x8 vb = *reinterpret_cast<const bf16x8*>(
                &kv[4096 + (lm + 16) * 128 + j * 16]);
            o1 = __builtin_amdgcn_mfma_f32_16x16x32_bf16(vb, pa, o1, 0, 0, 0);
        }
    }

    // final denominator: reduce partial l across the 4 lg groups of column lm
    float l = (l4[0] + l4[1]) + (l4[2] + l4[3]);
    l += __shfl_xor(l, 16);
    l += __shfl_xor(l, 32);
    float inv = 1.0f / l;

    __hip_bfloat16* cb = cws + ((size_t)b * S_LEN + qr0 + lm) * DMODEL + h * HD;
    union { unsigned int u[2]; bf16x4 v; } w0, w1;
    w0.u[0] = cvt_pk_bf16(o0[0] * inv, o0[1] * inv);
    w0.u[1] = cvt_pk_bf16(o0[2] * inv, o0[3] * inv);
    w1.u[0] = cvt_pk_bf16(o1[0] * inv, o1[1] * inv);
    w1.u[1] = cvt_pk_bf16(o1[2] * inv, o1[3] * inv);
    *reinterpret_cast<bf16x4*>(cb + lg * 4)      = w0.v;
    *reinterpret_cast<bf16x4*>(cb + 16 + lg * 4) = w1.v;
}

// ---------------------------------------------------------------------------
// Kernel 4: out = concat @ wo + bo — LDS-tiled (R7 attn recipe).
// Block tile 64x128, BK=64, 256 threads (2x2 waves, wave tile 32x64).
// Reg-staged LDS: global->reg, barrier, ds_write, barrier, prefetch next,
// compute. 16B-slot XOR swizzle j^=(row&7) on 128B rows (write & read).
// XCD pinning: bn = bi&7 -> each XCD keeps one 256KB Bt panel L2-resident.
// ---------------------------------------------------------------------------
__global__ __launch_bounds__(256) void out_gemm(
    const __hip_bfloat16* __restrict__ A,
    const __hip_bfloat16* __restrict__ Bt,
    const float* __restrict__ bo,
    float* __restrict__ out)
{
    const int tid = threadIdx.x;
    const int ln = tid & 63;
    const int w  = tid >> 6;
    const int lg = ln >> 4, lm = ln & 15;
    const int wr = w >> 1, wc = w & 1;        // 2x2 wave grid
    const int bi = blockIdx.x;
    const int bn = bi & 7;                    // XCD-pinned Bt panel
    const int bm = bi >> 3;                   // 0..63
    const int r0 = bm * 64;
    const int n0 = bn * 128;

    // LDS: A[64][64] bf16 swizzled @0 (8KB); Bt[128][64] swizzled @8192 (16KB)
    __shared__ __align__(16) char lds[24576];

    f32x4 acc[2][4];
#pragma unroll
    for (int m = 0; m < 2; ++m)
#pragma unroll
        for (int n = 0; n < 4; ++n)
            acc[m][n] = {0.f, 0.f, 0.f, 0.f};

    // staging slot for this thread: row = tid>>3, 16B slot j = tid&7
    const int srow = tid >> 3;                // 0..31
    const int sj   = tid & 7;
    const int swo  = srow * 128 + ((sj ^ (srow & 7)) << 4);  // (row+32)&7==row&7

    const __hip_bfloat16* Ab = A  + (size_t)r0 * DMODEL;
    const __hip_bfloat16* Bb = Bt + (size_t)n0 * DMODEL;

    // prologue: load K-tile 0
    uint4 ar0 = *reinterpret_cast<const uint4*>(Ab + (size_t)srow        * DMODEL + sj * 8);
    uint4 ar1 = *reinterpret_cast<const uint4*>(Ab + (size_t)(srow + 32) * DMODEL + sj * 8);
    uint4 br0 = *reinterpret_cast<const uint4*>(Bb + (size_t)srow        * DMODEL + sj * 8);
    uint4 br1 = *reinterpret_cast<const uint4*>(Bb + (size_t)(srow + 32) * DMODEL + sj * 8);
    uint4 br2 = *reinterpret_cast<const uint4*>(Bb + (size_t)(srow + 64) * DMODEL + sj * 8);
    uint4 br3 = *reinterpret_cast<const uint4*>(Bb + (size_t)(srow + 96) * DMODEL + sj * 8);

    for (int k0 = 0; k0 < DMODEL; k0 += 64) {
        if (k0) __syncthreads();
        *reinterpret_cast<uint4*>(&lds[swo])          = ar0;
        *reinterpret_cast<uint4*>(&lds[swo + 4096])   = ar1;
        *reinterpret_cast<uint4*>(&lds[8192 + swo])           = br0;
        *reinterpret_cast<uint4*>(&lds[8192 + swo + 4096])    = br1;
        *reinterpret_cast<uint4*>(&lds[8192 + swo + 8192])    = br2;
        *reinterpret_cast<uint4*>(&lds[8192 + swo + 12288])   = br3;
        __syncthreads();
        if (k0 + 64 < DMODEL) {
            const __hip_bfloat16* An = Ab + k0 + 64;
            const __hip_bfloat16* Bn = Bb + k0 + 64;
            ar0 = *reinterpret_cast<const uint4*>(An + (size_t)srow        * DMODEL + sj * 8);
            ar1 = *reinterpret_cast<const uint4*>(An + (size_t)(srow + 32) * DMODEL + sj * 8);
            br0 = *reinterpret_cast<const uint4*>(Bn + (size_t)srow        * DMODEL + sj * 8);
            br1 = *reinterpret_cast<const uint4*>(Bn + (size_t)(srow + 32) * DMODEL + sj * 8);
            br2 = *reinterpret_cast<const uint4*>(Bn + (size_t)(srow + 64) * DMODEL + sj * 8);
            br3 = *reinterpret_cast<const uint4*>(Bn + (size_t)(srow + 96) * DMODEL + sj * 8);
        }

#pragma unroll
        for (int kh = 0; kh < 2; ++kh) {
            bf16x8 af[2], bf[4];
#pragma unroll
            for (int m = 0; m < 2; ++m) {
                int row = wr * 32 + m * 16 + lm;
                af[m] = *reinterpret_cast<const bf16x8*>(
                    &lds[row * 128 + (((kh * 4 + lg) ^ (row & 7)) << 4)]);
            }
#pragma unroll
            for (int n = 0; n < 4; ++n) {
                int row = wc * 64 + n * 16 + lm;
                bf[n] = *reinterpret_cast<const bf16x8*>(
                    &lds[8192 + row * 128 + (((kh * 4 + lg) ^ (row & 7)) << 4)]);
            }
#pragma unroll
            for (int m = 0; m < 2; ++m)
#pragma unroll
                for (int n = 0; n < 4; ++n)
                    acc[m][n] = __builtin_amdgcn_mfma_f32_16x16x32_bf16(
                        af[m], bf[n], acc[m][n], 0, 0, 0);
        }
    }

    // epilogue: bias + fp32 store (C: row from A-side, col from Bt-side)
#pragma unroll
    for (int n = 0; n < 4; ++n) {
        int col = n0 + wc * 64 + n * 16 + lm;
        float bv = bo[col];
#pragma unroll
        for (int m = 0; m < 2; ++m) {
#pragma unroll
            for (int r = 0; r < 4; ++r) {
                int row = r0 + wr * 32 + m * 16 + lg * 4 + r;
                out[(size_t)row * DMODEL + col] = acc[m][n][r] + bv;
            }
        }
    }
}

// ---------------------------------------------------------------------------
extern "C" void kernel_launch(void* const* d_in, const int* in_sizes, int n_in,
                              void* d_out, int out_size, void* d_ws, size_t ws_size,
                              hipStream_t stream)
{
    const float* x  = (const float*)d_in[0];
    const float* wq = (const float*)d_in[1];
    const float* bq = (const float*)d_in[2];
    const float* wk = (const float*)d_in[3];
    const float* bk = (const float*)d_in[4];
    const float* wv = (const float*)d_in[5];
    const float* bv = (const float*)d_in[6];
    const float* wo = (const float*)d_in[7];
    const float* bo = (const float*)d_in[8];
    float* out = (float*)d_out;

    char* ws = (char*)d_ws;
    __hip_bfloat16* qws  = (__hip_bfloat16*)(ws);                        // 8 MB
    __hip_bfloat16* kws  = (__hip_bfloat16*)(ws + ((size_t)8  << 20));   // 8 MB
    __hip_bfloat16* vtws = (__hip_bfloat16*)(ws + ((size_t)16 << 20));   // 8 MB
    __hip_bfloat16* cws  = (__hip_bfloat16*)(ws + ((size_t)24 << 20));   // 8 MB
    __hip_bfloat16* wot  = (__hip_bfloat16*)(ws + ((size_t)32 << 20));   // 2 MB

    qkv_stage<<<dim3(NB * S_LEN / 16, 4), 256, 0, stream>>>(
        x, wq, bq, wk, bk, wv, bv, qws, kws, vtws);
    wo_transpose<<<dim3(16, 16), 256, 0, stream>>>(wo, wot);
    attn_kernel<<<NB * NH * (S_LEN / 64), 256, 0, stream>>>(qws, kws, vtws, cws);
    out_gemm<<<(NB * S_LEN / 64) * (DMODEL / 128), 256, 0, stream>>>(
        cws, wot, bo, out);
}

// Round 11
// 97.490 us; speedup vs baseline: 4.0153x; 1.1968x over previous
//
#include <hip/hip_runtime.h>
#include <hip/hip_bf16.h>

typedef __attribute__((ext_vector_type(8))) short bf16x8;
typedef __attribute__((ext_vector_type(4))) short bf16x4;
typedef __attribute__((ext_vector_type(4))) float f32x4;

#if defined(__has_builtin)
#if __has_builtin(__builtin_amdgcn_exp2f)
#define EXP2F(x) __builtin_amdgcn_exp2f(x)
#else
#define EXP2F(x) exp2f(x)
#endif
#else
#define EXP2F(x) exp2f(x)
#endif

#define S_LEN 2048
#define NH 32
#define HD 32
#define DMODEL 1024
#define NB 2

// pack two fp32 -> two bf16 (RNE) in one instruction
static __device__ __forceinline__ unsigned int cvt_pk_bf16(float lo, float hi) {
    unsigned int r;
    asm("v_cvt_pk_bf16_f32 %0, %1, %2" : "=v"(r) : "v"(lo), "v"(hi));
    return r;
}

// ---------------------------------------------------------------------------
// Kernel 1 (NEW): MFMA QKV projection.
// Work unit = 16 tokens x 1 head. Grid 1024 blocks x 4 waves x 2 units.
// Verified fragment relations only:
//   x A-frag  row=lm(token), k=lg*8+j           (R8 K-tile pattern)
//   W B-frag  col=lm(e),     k=lg*8+j           (R8 qb pattern)
//   Wv^T A-frag row=lm(e),   k=lg*8+j           (same gather)
//   C-layout  col=lm, row=4lg+r                 (R2/R8 epilogues)
//   bias via C operand                          (R3 zoff pattern)
// Q folded scale: Wq*SC, bq*SC  (SC = 1/sqrt(d)*log2 e).
// ---------------------------------------------------------------------------
__global__ __launch_bounds__(256) void qkv_mfma(
    const float* __restrict__ x,
    const float* __restrict__ wq, const float* __restrict__ bq,
    const float* __restrict__ wk, const float* __restrict__ bk,
    const float* __restrict__ wv, const float* __restrict__ bv,
    __hip_bfloat16* __restrict__ qws,
    __hip_bfloat16* __restrict__ kws,
    __hip_bfloat16* __restrict__ vtws)
{
    const int tid = threadIdx.x;
    const int w  = tid >> 6;
    const int ln = tid & 63;
    const int lg = ln >> 4, lm = ln & 15;

    const int bi = blockIdx.x;          // 0..1023
    const int tb = bi >> 2;             // token-16 block 0..255
    const int hq = bi & 3;              // head quarter
    const int t0 = tb * 16;             // flat token base (b*S + s)
    const int b  = t0 >> 11;
    const int s0 = t0 & 2047;

    const float SC = 0.1767766953f * 1.44269504089f;

    // --- loop-invariant W fragments ---
    bf16x8 wqB[2], wkB[2], wvA[2];
    f32x4 bqC[2], bkC[2], bvC[2];
#pragma unroll
    for (int et = 0; et < 2; ++et) {
        const int e = et * 16 + lm;
        union { unsigned int u4[4]; bf16x8 v; } tq, tk, tv;
#pragma unroll
        for (int jj = 0; jj < 4; ++jj) {
            int k0 = lg * 8 + jj * 2;
            tq.u4[jj] = cvt_pk_bf16(wq[k0 * 32 + e] * SC, wq[(k0 + 1) * 32 + e] * SC);
            tk.u4[jj] = cvt_pk_bf16(wk[k0 * 32 + e],      wk[(k0 + 1) * 32 + e]);
            tv.u4[jj] = cvt_pk_bf16(wv[k0 * 32 + e],      wv[(k0 + 1) * 32 + e]);
        }
        wqB[et] = tq.v; wkB[et] = tk.v; wvA[et] = tv.v;

        float bqe = bq[e] * SC;
        float bke = bk[e];
        bqC[et] = (f32x4){bqe, bqe, bqe, bqe};
        bkC[et] = (f32x4){bke, bke, bke, bke};
#pragma unroll
        for (int r = 0; r < 4; ++r)
            bvC[et][r] = bv[et * 16 + lg * 4 + r];
    }

#pragma unroll
    for (int u = 0; u < 2; ++u) {
        const int h = hq * 8 + w * 2 + u;

        // x fragment: x[token t0+lm][h*32 + lg*8 + 0..7] (fp32 -> bf16)
        const float* xp = x + (size_t)(t0 + lm) * DMODEL + h * 32 + lg * 8;
        float4 xlo = *reinterpret_cast<const float4*>(xp);
        float4 xhi = *reinterpret_cast<const float4*>(xp + 4);
        union { unsigned int u4[4]; bf16x8 v; } xa;
        xa.u4[0] = cvt_pk_bf16(xlo.x, xlo.y);
        xa.u4[1] = cvt_pk_bf16(xlo.z, xlo.w);
        xa.u4[2] = cvt_pk_bf16(xhi.x, xhi.y);
        xa.u4[3] = cvt_pk_bf16(xhi.z, xhi.w);

        const int bh = b * NH + h;
        __hip_bfloat16* qrow = qws + ((size_t)bh * S_LEN + s0) * HD;
        __hip_bfloat16* krow = kws + ((size_t)bh * S_LEN + s0) * HD;
        __hip_bfloat16* vrow = vtws + (size_t)bh * HD * S_LEN + s0;

#pragma unroll
        for (int et = 0; et < 2; ++et) {
            f32x4 qd = __builtin_amdgcn_mfma_f32_16x16x32_bf16(xa.v, wqB[et], bqC[et], 0, 0, 0);
            f32x4 kd = __builtin_amdgcn_mfma_f32_16x16x32_bf16(xa.v, wkB[et], bkC[et], 0, 0, 0);
            f32x4 vd = __builtin_amdgcn_mfma_f32_16x16x32_bf16(wvA[et], xa.v, bvC[et], 0, 0, 0);
#pragma unroll
            for (int r = 0; r < 4; ++r) {
                int srow = 4 * lg + r;          // token offset within the 16
                qrow[(size_t)srow * HD + et * 16 + lm] = __float2bfloat16(qd[r]);
                krow[(size_t)srow * HD + et * 16 + lm] = __float2bfloat16(kd[r]);
                vrow[(size_t)(et * 16 + 4 * lg + r) * S_LEN + lm] = __float2bfloat16(vd[r]);
            }
        }
    }
}

// ---------------------------------------------------------------------------
// Kernel 2: wo [K][N] fp32 -> wot [N][K] bf16 (unchanged, verified)
// ---------------------------------------------------------------------------
__global__ __launch_bounds__(256) void wo_transpose(
    const float* __restrict__ wo, __hip_bfloat16* __restrict__ wot)
{
    __shared__ float t[64][65];
    const int bx = blockIdx.x;
    const int by = blockIdx.y;
    const int tid = threadIdx.x;
    const int col = tid & 63, row4 = tid >> 6;
#pragma unroll
    for (int i = 0; i < 16; ++i) {
        int r = i * 4 + row4;
        t[r][col] = wo[(size_t)(bx * 64 + r) * DMODEL + by * 64 + col];
    }
    __syncthreads();
#pragma unroll
    for (int i = 0; i < 16; ++i) {
        int r = i * 4 + row4;
        wot[(size_t)(by * 64 + r) * DMODEL + bx * 64 + col] =
            __float2bfloat16(t[col][r]);
    }
}

// ---------------------------------------------------------------------------
// Kernel 3: flash attention — BYTE-EXACT revert to the R8 version that
// passed at 75 us (grid 2048, 64-row blocks, 16 q-rows/wave, block-shared
// K/V LDS staging, swapped QK^T, fixed-offset softmax, LDS P strip).
// ---------------------------------------------------------------------------
__global__ __launch_bounds__(256) void attn_kernel(
    const __hip_bfloat16* __restrict__ qws,
    const __hip_bfloat16* __restrict__ kws,
    const __hip_bfloat16* __restrict__ vtws,
    __hip_bfloat16* __restrict__ cws)
{
    const int tid = threadIdx.x;
    const int w  = tid >> 6;
    const int ln = tid & 63;
    const int lg = ln >> 4;   // 16-lane group 0..3
    const int lm = ln & 15;

    // XCD-aware decode (R5-verified): heads 8x..8x+7 pinned to XCD x
    const int bi  = blockIdx.x;
    const int xcd = bi & 7;
    const int idx = bi >> 3;                   // 0..255
    const int qt  = idx & 31;
    const int bh  = (xcd << 3) | (idx >> 5);   // b*32+h
    const int b   = bh >> 5;
    const int h   = bh & 31;

    const __hip_bfloat16* qp = qws + (size_t)bh * S_LEN * HD;
    const char* kpb = (const char*)(kws  + (size_t)bh * S_LEN * HD);
    const char* vpb = (const char*)(vtws + (size_t)bh * HD * S_LEN);

    const int qr0 = qt * 64 + w * 16;

    // Q as B-fragment: col = q = lm, k = d = lg*8+j
    bf16x8 qb = *reinterpret_cast<const bf16x8*>(qp + (size_t)(qr0 + lm) * HD + lg * 8);

    // LDS: K tile [0,4096) linear; V tile [4096,8192) 16B-slot swizzled
    __shared__ __align__(16) char kv[8192];
    __shared__ __align__(16) __hip_bfloat16 plds_all[4][16][72];
    __hip_bfloat16 (*plds)[72] = plds_all[w];

    f32x4 l4 = {0.f, 0.f, 0.f, 0.f};
    f32x4 o0 = {0.f, 0.f, 0.f, 0.f};   // O^T[d=4lg+r][q=lm]
    f32x4 o1 = {0.f, 0.f, 0.f, 0.f};   // O^T[16+4lg+r][q=lm]
    const f32x4 zoff = {-8.f, -8.f, -8.f, -8.f};

    // staging addresses: thread tid owns 16B slot tid of each tile
    const int vrow  = tid >> 3;                       // V^T row (d), 0..31
    const int vslot = tid & 7;                        // 16B slot within row
    const size_t vsrc = (size_t)vrow * (S_LEN * 2) +
                        (size_t)(vslot ^ (vrow & 7)) * 16;   // swizzled source

    // prologue: load tile 0 into registers
    uint4 kreg = *reinterpret_cast<const uint4*>(kpb + tid * 16);
    uint4 vreg = *reinterpret_cast<const uint4*>(vpb + vsrc);

    for (int kt = 0; kt < S_LEN / 64; ++kt) {
        if (kt) __syncthreads();                      // readers done with buffer
        *reinterpret_cast<uint4*>(&kv[tid * 16])        = kreg;
        *reinterpret_cast<uint4*>(&kv[4096 + tid * 16]) = vreg;
        __syncthreads();                              // staged data visible
        if (kt + 1 < S_LEN / 64) {                    // issue next-tile loads now
            kreg = *reinterpret_cast<const uint4*>(
                kpb + (size_t)(kt + 1) * 4096 + tid * 16);
            vreg = *reinterpret_cast<const uint4*>(
                vpb + vsrc + (size_t)(kt + 1) * 128);
        }

        // S^T chunks: s[c][r] = score(q=lm, k=16c+4lg+r) - 8
        f32x4 s[4];
#pragma unroll
        for (int c = 0; c < 4; ++c) {
            bf16x8 kf = *reinterpret_cast<const bf16x8*>(
                &kv[c * 1024 + lm * 64 + lg * 16]);
            s[c] = __builtin_amdgcn_mfma_f32_16x16x32_bf16(kf, qb, zoff, 0, 0, 0);
        }

        // p = exp2(s-8); accumulate denominator; pack into P[q][k] LDS strip
#pragma unroll
        for (int c = 0; c < 4; ++c) {
            float p0 = EXP2F(s[c][0]);
            float p1 = EXP2F(s[c][1]);
            float p2 = EXP2F(s[c][2]);
            float p3 = EXP2F(s[c][3]);
            l4[0] += p0; l4[1] += p1; l4[2] += p2; l4[3] += p3;
            *reinterpret_cast<uint2*>(&plds[lm][c * 16 + lg * 4]) =
                make_uint2(cvt_pk_bf16(p0, p1), cvt_pk_bf16(p2, p3));
        }

        // PV: O^T += V^T * P^T; A = V^T rows from swizzled LDS (16B reads)
#pragma unroll
        for (int ks = 0; ks < 2; ++ks) {
            bf16x8 pa = *reinterpret_cast<const bf16x8*>(
                &plds[lm][ks * 32 + lg * 8]);
            int j = (ks * 4 + lg) ^ (lm & 7);
            bf16x8 va = *reinterpret_cast<const bf16x8*>(
                &kv[4096 + lm * 128 + j * 16]);
            o0 = __builtin_amdgcn_mfma_f32_16x16x32_bf16(va, pa, o0, 0, 0, 0);
            bf16x8 vb = *reinterpret_cast<const bf16x8*>(
                &kv[4096 + (lm + 16) * 128 + j * 16]);
            o1 = __builtin_amdgcn_mfma_f32_16x16x32_bf16(vb, pa, o1, 0, 0, 0);
        }
    }

    // final denominator: reduce partial l across the 4 lg groups of column lm
    float l = (l4[0] + l4[1]) + (l4[2] + l4[3]);
    l += __shfl_xor(l, 16);
    l += __shfl_xor(l, 32);
    float inv = 1.0f / l;

    __hip_bfloat16* cb = cws + ((size_t)b * S_LEN + qr0 + lm) * DMODEL + h * HD;
    union { unsigned int u[2]; bf16x4 v; } w0, w1;
    w0.u[0] = cvt_pk_bf16(o0[0] * inv, o0[1] * inv);
    w0.u[1] = cvt_pk_bf16(o0[2] * inv, o0[3] * inv);
    w1.u[0] = cvt_pk_bf16(o1[0] * inv, o1[1] * inv);
    w1.u[1] = cvt_pk_bf16(o1[2] * inv, o1[3] * inv);
    *reinterpret_cast<bf16x4*>(cb + lg * 4)      = w0.v;
    *reinterpret_cast<bf16x4*>(cb + 16 + lg * 4) = w1.v;
}

// ---------------------------------------------------------------------------
// Kernel 4: out = concat @ wo + bo — LDS-tiled (unchanged from R8, verified)
// ---------------------------------------------------------------------------
__global__ __launch_bounds__(256) void out_gemm(
    const __hip_bfloat16* __restrict__ A,
    const __hip_bfloat16* __restrict__ Bt,
    const float* __restrict__ bo,
    float* __restrict__ out)
{
    const int tid = threadIdx.x;
    const int ln = tid & 63;
    const int w  = tid >> 6;
    const int lg = ln >> 4, lm = ln & 15;
    const int wr = w >> 1, wc = w & 1;
    const int bi = blockIdx.x;
    const int bn = bi & 7;
    const int bm = bi >> 3;
    const int r0 = bm * 64;
    const int n0 = bn * 128;

    __shared__ __align__(16) char lds[24576];

    f32x4 acc[2][4];
#pragma unroll
    for (int m = 0; m < 2; ++m)
#pragma unroll
        for (int n = 0; n < 4; ++n)
            acc[m][n] = {0.f, 0.f, 0.f, 0.f};

    const int srow = tid >> 3;
    const int sj   = tid & 7;
    const int swo  = srow * 128 + ((sj ^ (srow & 7)) << 4);

    const __hip_bfloat16* Ab = A  + (size_t)r0 * DMODEL;
    const __hip_bfloat16* Bb = Bt + (size_t)n0 * DMODEL;

    uint4 ar0 = *reinterpret_cast<const uint4*>(Ab + (size_t)srow        * DMODEL + sj * 8);
    uint4 ar1 = *reinterpret_cast<const uint4*>(Ab + (size_t)(srow + 32) * DMODEL + sj * 8);
    uint4 br0 = *reinterpret_cast<const uint4*>(Bb + (size_t)srow        * DMODEL + sj * 8);
    uint4 br1 = *reinterpret_cast<const uint4*>(Bb + (size_t)(srow + 32) * DMODEL + sj * 8);
    uint4 br2 = *reinterpret_cast<const uint4*>(Bb + (size_t)(srow + 64) * DMODEL + sj * 8);
    uint4 br3 = *reinterpret_cast<const uint4*>(Bb + (size_t)(srow + 96) * DMODEL + sj * 8);

    for (int k0 = 0; k0 < DMODEL; k0 += 64) {
        if (k0) __syncthreads();
        *reinterpret_cast<uint4*>(&lds[swo])          = ar0;
        *reinterpret_cast<uint4*>(&lds[swo + 4096])   = ar1;
        *reinterpret_cast<uint4*>(&lds[8192 + swo])           = br0;
        *reinterpret_cast<uint4*>(&lds[8192 + swo + 4096])    = br1;
        *reinterpret_cast<uint4*>(&lds[8192 + swo + 8192])    = br2;
        *reinterpret_cast<uint4*>(&lds[8192 + swo + 12288])   = br3;
        __syncthreads();
        if (k0 + 64 < DMODEL) {
            const __hip_bfloat16* An = Ab + k0 + 64;
            const __hip_bfloat16* Bn = Bb + k0 + 64;
            ar0 = *reinterpret_cast<const uint4*>(An + (size_t)srow        * DMODEL + sj * 8);
            ar1 = *reinterpret_cast<const uint4*>(An + (size_t)(srow + 32) * DMODEL + sj * 8);
            br0 = *reinterpret_cast<const uint4*>(Bn + (size_t)srow        * DMODEL + sj * 8);
            br1 = *reinterpret_cast<const uint4*>(Bn + (size_t)(srow + 32) * DMODEL + sj * 8);
            br2 = *reinterpret_cast<const uint4*>(Bn + (size_t)(srow + 64) * DMODEL + sj * 8);
            br3 = *reinterpret_cast<const uint4*>(Bn + (size_t)(srow + 96) * DMODEL + sj * 8);
        }

#pragma unroll
        for (int kh = 0; kh < 2; ++kh) {
            bf16x8 af[2], bf[4];
#pragma unroll
            for (int m = 0; m < 2; ++m) {
                int row = wr * 32 + m * 16 + lm;
                af[m] = *reinterpret_cast<const bf16x8*>(
                    &lds[row * 128 + (((kh * 4 + lg) ^ (row & 7)) << 4)]);
            }
#pragma unroll
            for (int n = 0; n < 4; ++n) {
                int row = wc * 64 + n * 16 + lm;
                bf[n] = *reinterpret_cast<const bf16x8*>(
                    &lds[8192 + row * 128 + (((kh * 4 + lg) ^ (row & 7)) << 4)]);
            }
#pragma unroll
            for (int m = 0; m < 2; ++m)
#pragma unroll
                for (int n = 0; n < 4; ++n)
                    acc[m][n] = __builtin_amdgcn_mfma_f32_16x16x32_bf16(
                        af[m], bf[n], acc[m][n], 0, 0, 0);
        }
    }

#pragma unroll
    for (int n = 0; n < 4; ++n) {
        int col = n0 + wc * 64 + n * 16 + lm;
        float bv = bo[col];
#pragma unroll
        for (int m = 0; m < 2; ++m) {
#pragma unroll
            for (int r = 0; r < 4; ++r) {
                int row = r0 + wr * 32 + m * 16 + lg * 4 + r;
                out[(size_t)row * DMODEL + col] = acc[m][n][r] + bv;
            }
        }
    }
}

// ---------------------------------------------------------------------------
extern "C" void kernel_launch(void* const* d_in, const int* in_sizes, int n_in,
                              void* d_out, int out_size, void* d_ws, size_t ws_size,
                              hipStream_t stream)
{
    const float* x  = (const float*)d_in[0];
    const float* wq = (const float*)d_in[1];
    const float* bq = (const float*)d_in[2];
    const float* wk = (const float*)d_in[3];
    const float* bk = (const float*)d_in[4];
    const float* wv = (const float*)d_in[5];
    const float* bv = (const float*)d_in[6];
    const float* wo = (const float*)d_in[7];
    const float* bo = (const float*)d_in[8];
    float* out = (float*)d_out;

    char* ws = (char*)d_ws;
    __hip_bfloat16* qws  = (__hip_bfloat16*)(ws);                        // 8 MB
    __hip_bfloat16* kws  = (__hip_bfloat16*)(ws + ((size_t)8  << 20));   // 8 MB
    __hip_bfloat16* vtws = (__hip_bfloat16*)(ws + ((size_t)16 << 20));   // 8 MB
    __hip_bfloat16* cws  = (__hip_bfloat16*)(ws + ((size_t)24 << 20));   // 8 MB
    __hip_bfloat16* wot  = (__hip_bfloat16*)(ws + ((size_t)32 << 20));   // 2 MB

    qkv_mfma<<<1024, 256, 0, stream>>>(
        x, wq, bq, wk, bk, wv, bv, qws, kws, vtws);
    wo_transpose<<<dim3(16, 16), 256, 0, stream>>>(wo, wot);
    attn_kernel<<<NB * NH * (S_LEN / 64), 256, 0, stream>>>(qws, kws, vtws, cws);
    out_gemm<<<(NB * S_LEN / 64) * (DMODEL / 128), 256, 0, stream>>>(
        cws, wot, bo, out);
}